// Round 5
// baseline (134.939 us; speedup 1.0000x reference)
//
#include <hip/hip_runtime.h>

// Fused MHA: x->QKV proj (bf16 MFMA) -> causal flash attn -> O proj.
// B=2, T=2048, D=1024, H=16, HD=64.
// Round 5: triple-buffered staging + counted vmcnt (never 0 in loop) in all
// MFMA kernels; raw s_barrier (no cross-wave ds hazards).

#define DEV __device__ __forceinline__

typedef __attribute__((ext_vector_type(8))) __bf16 bf16x8;
typedef __attribute__((ext_vector_type(4))) float f32x4;

DEV unsigned short f2bf(float f) {
  union { float f; unsigned u; } c;
  c.f = f;
  unsigned u = c.u + 0x7FFFu + ((c.u >> 16) & 1u);  // RTNE
  return (unsigned short)(u >> 16);
}

DEV unsigned cvtpk(float lo, float hi) {
  unsigned r;
  asm("v_cvt_pk_bf16_f32 %0, %1, %2" : "=v"(r) : "v"(lo), "v"(hi));
  return r;
}

DEV void gload16(const unsigned short* g, unsigned short* l) {
  __builtin_amdgcn_global_load_lds(
      (const __attribute__((address_space(1))) unsigned int*)g,
      (__attribute__((address_space(3))) unsigned int*)l, 16, 0, 0);
}

DEV f32x4 mfma16(bf16x8 a, bf16x8 b, f32x4 c) {
  return __builtin_amdgcn_mfma_f32_16x16x32_bf16(a, b, c, 0, 0, 0);
}

#define WAITVM(n) asm volatile("s_waitcnt vmcnt(" #n ")" ::: "memory")
#define BAR() __builtin_amdgcn_s_barrier()
#define SCHEDB() __builtin_amdgcn_sched_barrier(0)

// ---------------- fp32 -> bf16 convert (all 5 tensors, one launch) -------
__global__ __launch_bounds__(256) void k_cvt_all(
    const float* __restrict__ x, const float* __restrict__ wq,
    const float* __restrict__ wk, const float* __restrict__ wv,
    const float* __restrict__ wo, unsigned short* __restrict__ dst) {
  int i = blockIdx.x * blockDim.x + threadIdx.x;  // float4 index
  const float* s;
  int off;
  if (i < 1048576) {
    s = x; off = i;
  } else {
    int j = i - 1048576;
    int w = j >> 18;
    off = j & 262143;
    s = (w == 0) ? wq : (w == 1) ? wk : (w == 2) ? wv : wo;
  }
  float4 v = reinterpret_cast<const float4*>(s)[off];
  uint2 o;
  o.x = (unsigned)f2bf(v.x) | ((unsigned)f2bf(v.y) << 16);
  o.y = (unsigned)f2bf(v.z) | ((unsigned)f2bf(v.w) << 16);
  reinterpret_cast<uint2*>(dst)[i] = o;
}

// ---------------- 128x128 bf16 GEMM core (C = A * W^T), K=1024 ----------
// Triple-buffered: stage(t+2) each iter, vmcnt(8) drains only tile t.
DEV void gemm_stage(const unsigned short* __restrict__ A,
                    const unsigned short* __restrict__ W,
                    unsigned short* la, unsigned short* lb,
                    int m0, int n0, int k0, int tid) {
#pragma unroll
  for (int i = 0; i < 2; ++i) {
    const int c = i * 256 + tid;
    const int row = c >> 2;
    const int cb = (c & 3) << 4;
    gload16(A + (m0 + row) * 1024 + k0 + (cb >> 1),
            (unsigned short*)((char*)la + c * 16));
    gload16(W + (n0 + row) * 1024 + k0 + (cb >> 1),
            (unsigned short*)((char*)lb + c * 16));
  }
}

DEV void gemm_core_128(const unsigned short* __restrict__ A,
                       const unsigned short* __restrict__ W,
                       unsigned short (*la)[128 * 32],
                       unsigned short (*lb)[128 * 32],
                       int m0, int n0, f32x4 (&acc)[4][4]) {
  const int tid = threadIdx.x;
  const int lane = tid & 63;
  const int wave = tid >> 6;
  const int wm = (wave >> 1) * 64, wn = (wave & 1) * 64;

  gemm_stage(A, W, la[0], lb[0], m0, n0, 0, tid);
  gemm_stage(A, W, la[1], lb[1], m0, n0, 32, tid);
  WAITVM(4);  // tile 0 landed
  BAR();

  for (int kt = 0; kt < 32; ++kt) {
    const int nx = (kt + 2 < 32) ? kt + 2 : 31;  // clamp: redundant re-stage
    const int sb = (kt + 2) % 3, cb = kt % 3;
    gemm_stage(A, W, la[sb], lb[sb], m0, n0, nx * 32, tid);
    WAITVM(8);  // tiles kt+1, kt+2 stay in flight; kt drained
    BAR();
    SCHEDB();
    bf16x8 af[4], bfr[4];
#pragma unroll
    for (int m = 0; m < 4; ++m)
      af[m] = *reinterpret_cast<const bf16x8*>(
          &la[cb][(wm + m * 16 + (lane & 15)) * 32 + ((lane >> 4) << 3)]);
#pragma unroll
    for (int n = 0; n < 4; ++n)
      bfr[n] = *reinterpret_cast<const bf16x8*>(
          &lb[cb][(wn + n * 16 + (lane & 15)) * 32 + ((lane >> 4) << 3)]);
#pragma unroll
    for (int m = 0; m < 4; ++m)
#pragma unroll
      for (int n = 0; n < 4; ++n)
        acc[m][n] = mfma16(af[m], bfr[n], acc[m][n]);
    BAR();  // all waves done with buf cb before it is re-staged
  }
}

// ---------------- QKV projection ----------------
// Q is pre-scaled by 0.125*log2(e) so attn scores land in exp2 domain.
__global__ __launch_bounds__(256) void k_gemm_qkv(
    const unsigned short* __restrict__ X, const unsigned short* __restrict__ Wq,
    const unsigned short* __restrict__ Wk, const unsigned short* __restrict__ Wv,
    const float* __restrict__ bq, const float* __restrict__ bk,
    const float* __restrict__ bv, unsigned short* __restrict__ Qo,
    unsigned short* __restrict__ Ko, unsigned short* __restrict__ Vo) {
  __shared__ unsigned short la[3][128 * 32], lb[3][128 * 32];
  const int mode = blockIdx.z;
  const unsigned short* W = (mode == 0) ? Wq : (mode == 1) ? Wk : Wv;
  const float* bias = (mode == 0) ? bq : (mode == 1) ? bk : bv;
  const int m0 = blockIdx.y * 128, n0 = blockIdx.x * 128;
  f32x4 acc[4][4] = {};
  gemm_core_128(X, W, la, lb, m0, n0, acc);

  const int lane = threadIdx.x & 63, wave = threadIdx.x >> 6;
  const int wm = (wave >> 1) * 64, wn = (wave & 1) * 64;
#pragma unroll
  for (int m = 0; m < 4; ++m) {
    const int rbase = m0 + wm + m * 16 + ((lane >> 4) << 2);
    const int b = rbase >> 11;
    const int tb = rbase & 2047;
#pragma unroll
    for (int n = 0; n < 4; ++n) {
      const int col = n0 + wn + n * 16 + (lane & 15);
      const float bb = bias[col];
      const int h = col >> 6, hd = col & 63;
      if (mode == 2) {
        unsigned short e0 = f2bf(acc[m][n][0] + bb);
        unsigned short e1 = f2bf(acc[m][n][1] + bb);
        unsigned short e2 = f2bf(acc[m][n][2] + bb);
        unsigned short e3 = f2bf(acc[m][n][3] + bb);
        uint2 pk;
        pk.x = (unsigned)e0 | ((unsigned)e1 << 16);
        pk.y = (unsigned)e2 | ((unsigned)e3 << 16);
        *reinterpret_cast<uint2*>(
            &Vo[(((b << 4) + h) * 64 + hd) * 2048 + tb]) = pk;
      } else {
#pragma unroll
        for (int r = 0; r < 4; ++r) {
          float v = acc[m][n][r] + bb;
          const int t = tb + r;
          if (mode == 0)
            Qo[((((b << 4) + h) * 2048 + t) << 6) + hd] =
                f2bf(v * 0.180336880f);  // 0.125 * log2(e)
          else
            Ko[((((b << 4) + h) * 2048 + t) << 6) + hd] = f2bf(v);
        }
      }
    }
  }
}

// ---------------- output projection (128x64 tiles, fp32 out + bias) ------
__global__ __launch_bounds__(256) void k_gemm_out(
    const unsigned short* __restrict__ Ctx, const unsigned short* __restrict__ Wo,
    const float* __restrict__ bo, float* __restrict__ Out) {
  __shared__ unsigned short la[3][128 * 32], lb[3][64 * 32];
  const int tid = threadIdx.x;
  const int lane = tid & 63, wave = tid >> 6;
  const int m0 = blockIdx.y * 128, n0 = blockIdx.x * 64;
  const int wm = (wave >> 1) * 64, wn = (wave & 1) * 32;
  f32x4 acc[4][2] = {};

  // stage = 3 gloads/thread
#define STG_OUT(buf, k0)                                                     \
  {                                                                          \
    _Pragma("unroll") for (int i = 0; i < 2; ++i) {                          \
      const int c = i * 256 + tid;                                           \
      gload16(Ctx + (m0 + (c >> 2)) * 1024 + (k0) + ((c & 3) << 3),          \
              (unsigned short*)((char*)la[buf] + c * 16));                   \
    }                                                                        \
    gload16(Wo + (n0 + (tid >> 2)) * 1024 + (k0) + ((tid & 3) << 3),         \
            (unsigned short*)((char*)lb[buf] + tid * 16));                   \
  }

  STG_OUT(0, 0);
  STG_OUT(1, 32);
  WAITVM(3);
  BAR();

  for (int kt = 0; kt < 32; ++kt) {
    const int nx = (kt + 2 < 32) ? kt + 2 : 31;
    const int sb = (kt + 2) % 3, cb = kt % 3;
    STG_OUT(sb, nx * 32);
    WAITVM(6);
    BAR();
    SCHEDB();
    bf16x8 af[4], bfr[2];
#pragma unroll
    for (int m = 0; m < 4; ++m)
      af[m] = *reinterpret_cast<const bf16x8*>(
          &la[cb][(wm + m * 16 + (lane & 15)) * 32 + ((lane >> 4) << 3)]);
#pragma unroll
    for (int n = 0; n < 2; ++n)
      bfr[n] = *reinterpret_cast<const bf16x8*>(
          &lb[cb][(wn + n * 16 + (lane & 15)) * 32 + ((lane >> 4) << 3)]);
#pragma unroll
    for (int m = 0; m < 4; ++m)
#pragma unroll
      for (int n = 0; n < 2; ++n)
        acc[m][n] = mfma16(af[m], bfr[n], acc[m][n]);
    BAR();
  }
#undef STG_OUT

#pragma unroll
  for (int m = 0; m < 4; ++m) {
    const int rbase = m0 + wm + m * 16 + ((lane >> 4) << 2);
#pragma unroll
    for (int n = 0; n < 2; ++n) {
      const int col = n0 + wn + n * 16 + (lane & 15);
      const float bb = bo[col];
#pragma unroll
      for (int r = 0; r < 4; ++r)
        Out[(rbase + r) * 1024 + col] = acc[m][n][r] + bb;
    }
  }
}

// ---------------- causal flash attention (swapped-QK^T, fixed-max) -------
// Q: [32][2048][64] bf16 (pre-scaled 0.125*log2e), K: [32][2048][64],
// Vt: [32][64][2048]. Lane owns q = lane&15, k-subset = 16n+4g+r (g=lane>>4).
// No max tracking: P = exp2(S2) directly; normalized by l at end.

DEV void attn_stage(const unsigned short* __restrict__ Kb,
                    const unsigned short* __restrict__ Vb,
                    unsigned short* lk, unsigned short* lv, int kv0, int tid) {
#pragma unroll
  for (int i = 0; i < 2; ++i) {
    const int c = i * 256 + tid;
    const int row = c >> 3;
    const int cb = (c & 7) << 4;
    const int scb = cb ^ ((row & 7) << 4);  // pre-swizzle global source
    gload16(Kb + (kv0 + row) * 64 + (scb >> 1),
            (unsigned short*)((char*)lk + c * 16));
    gload16(Vb + row * 2048 + kv0 + (scb >> 1),
            (unsigned short*)((char*)lv + c * 16));
  }
}

// single-tile step (B only)
DEV void attn_step(const unsigned short* lk, const unsigned short* lv,
                   unsigned short (&lp)[16][72], const bf16x8 (&qf)[2],
                   f32x4 (&o)[4], float& lsum, int lane, int qloc, bool diag) {
  const int g = lane >> 4;
  f32x4 st[4];
#pragma unroll
  for (int n = 0; n < 4; ++n) {
    f32x4 z = {};
    const int row = n * 16 + (lane & 15);
    const int sw = (row & 7) << 4;
#pragma unroll
    for (int kk = 0; kk < 2; ++kk) {
      bf16x8 kf = *reinterpret_cast<const bf16x8*>(
          (char*)lk + row * 128 + ((kk * 64 + (g << 4)) ^ sw));
      z = mfma16(kf, qf[kk], z);
    }
    st[n] = z;
  }
  if (diag) {
#pragma unroll
    for (int n = 0; n < 4; ++n)
#pragma unroll
      for (int r = 0; r < 4; ++r)
        if (n * 16 + g * 4 + r > qloc) st[n][r] = -1e30f;
  }
  float rs = 0.f;
#pragma unroll
  for (int n = 0; n < 4; ++n)
#pragma unroll
    for (int r = 0; r < 4; ++r) {
      float p = exp2f(st[n][r]);
      st[n][r] = p;
      rs += p;
    }
  lsum += rs;
#pragma unroll
  for (int n = 0; n < 4; ++n) {
    uint2 w;
    w.x = cvtpk(st[n][0], st[n][1]);
    w.y = cvtpk(st[n][2], st[n][3]);
    *reinterpret_cast<uint2*>(&lp[lane & 15][n * 16 + g * 4]) = w;
  }
  asm volatile("s_waitcnt lgkmcnt(0)" ::: "memory");
  SCHEDB();
  bf16x8 pb[2];
  pb[0] = *reinterpret_cast<const bf16x8*>(&lp[lane & 15][g * 8]);
  pb[1] = *reinterpret_cast<const bf16x8*>(&lp[lane & 15][32 + g * 8]);
#pragma unroll
  for (int h = 0; h < 4; ++h) {
    const int row = h * 16 + (lane & 15);
    const int sw = (row & 7) << 4;
#pragma unroll
    for (int kk = 0; kk < 2; ++kk) {
      bf16x8 vf = *reinterpret_cast<const bf16x8*>(
          (char*)lv + row * 128 + ((kk * 64 + (g << 4)) ^ sw));
      o[h] = mfma16(vf, pb[kk], o[h]);
    }
  }
}

// dual-tile step: shares kf/vf fragment loads between q-tiles A and B.
DEV void attn_step_dual(const unsigned short* lk, const unsigned short* lv,
                        unsigned short (&lpA)[16][72],
                        unsigned short (&lpB)[16][72],
                        const bf16x8 (&qfA)[2], const bf16x8 (&qfB)[2],
                        f32x4 (&oA)[4], f32x4 (&oB)[4], float& lsA, float& lsB,
                        int lane, int qloc, bool diagA) {
  const int g = lane >> 4;
  f32x4 sA[4], sB[4];
#pragma unroll
  for (int n = 0; n < 4; ++n) {
    f32x4 zA = {}, zB = {};
    const int row = n * 16 + (lane & 15);
    const int sw = (row & 7) << 4;
#pragma unroll
    for (int kk = 0; kk < 2; ++kk) {
      bf16x8 kf = *reinterpret_cast<const bf16x8*>(
          (char*)lk + row * 128 + ((kk * 64 + (g << 4)) ^ sw));
      zB = mfma16(kf, qfB[kk], zB);
      zA = mfma16(kf, qfA[kk], zA);
    }
    sA[n] = zA;
    sB[n] = zB;
  }
  if (diagA) {
#pragma unroll
    for (int n = 0; n < 4; ++n)
#pragma unroll
      for (int r = 0; r < 4; ++r)
        if (n * 16 + g * 4 + r > qloc) sA[n][r] = -1e30f;
  }
  float rsA = 0.f, rsB = 0.f;
#pragma unroll
  for (int n = 0; n < 4; ++n)
#pragma unroll
    for (int r = 0; r < 4; ++r) {
      float pA = exp2f(sA[n][r]);
      float pB = exp2f(sB[n][r]);
      sA[n][r] = pA;
      sB[n][r] = pB;
      rsA += pA;
      rsB += pB;
    }
  lsA += rsA;
  lsB += rsB;
#pragma unroll
  for (int n = 0; n < 4; ++n) {
    uint2 wA, wB;
    wA.x = cvtpk(sA[n][0], sA[n][1]);
    wA.y = cvtpk(sA[n][2], sA[n][3]);
    wB.x = cvtpk(sB[n][0], sB[n][1]);
    wB.y = cvtpk(sB[n][2], sB[n][3]);
    *reinterpret_cast<uint2*>(&lpA[lane & 15][n * 16 + g * 4]) = wA;
    *reinterpret_cast<uint2*>(&lpB[lane & 15][n * 16 + g * 4]) = wB;
  }
  asm volatile("s_waitcnt lgkmcnt(0)" ::: "memory");
  SCHEDB();
  bf16x8 pbA[2], pbB[2];
  pbA[0] = *reinterpret_cast<const bf16x8*>(&lpA[lane & 15][g * 8]);
  pbA[1] = *reinterpret_cast<const bf16x8*>(&lpA[lane & 15][32 + g * 8]);
  pbB[0] = *reinterpret_cast<const bf16x8*>(&lpB[lane & 15][g * 8]);
  pbB[1] = *reinterpret_cast<const bf16x8*>(&lpB[lane & 15][32 + g * 8]);
#pragma unroll
  for (int h = 0; h < 4; ++h) {
    const int row = h * 16 + (lane & 15);
    const int sw = (row & 7) << 4;
#pragma unroll
    for (int kk = 0; kk < 2; ++kk) {
      bf16x8 vf = *reinterpret_cast<const bf16x8*>(
          (char*)lv + row * 128 + ((kk * 64 + (g << 4)) ^ sw));
      oB[h] = mfma16(vf, pbB[kk], oB[h]);
      oA[h] = mfma16(vf, pbA[kk], oA[h]);
    }
  }
}

DEV void attn_epi(unsigned short* __restrict__ Ctx,
                  unsigned short (&lp)[16][72], const f32x4 (&o)[4],
                  float lsum, int b, int hh, int qbase, int lane) {
  float lt = lsum;
  lt += __shfl_xor(lt, 16);
  lt += __shfl_xor(lt, 32);
  const float inv = 1.f / lt;
  const int g = lane >> 4;
#pragma unroll
  for (int h = 0; h < 4; ++h) {
    uint2 w;
    w.x = cvtpk(o[h][0] * inv, o[h][1] * inv);
    w.y = cvtpk(o[h][2] * inv, o[h][3] * inv);
    *reinterpret_cast<uint2*>(&lp[lane & 15][h * 16 + g * 4]) = w;
  }
  asm volatile("s_waitcnt lgkmcnt(0)" ::: "memory");
  SCHEDB();
#pragma unroll
  for (int it = 0; it < 2; ++it) {
    const int q = (lane >> 3) + it * 8;
    const int ck = (lane & 7) * 8;
    uint4 v = *reinterpret_cast<const uint4*>(&lp[q][ck]);
    *reinterpret_cast<uint4*>(
        &Ctx[(b * 2048 + qbase + q) * 1024 + hh * 64 + ck]) = v;
  }
}

__global__ __launch_bounds__(256) void k_attn(
    const unsigned short* __restrict__ Q, const unsigned short* __restrict__ K,
    const unsigned short* __restrict__ Vt, unsigned short* __restrict__ Ctx) {
  __shared__ unsigned short lk[3][64 * 64];
  __shared__ unsigned short lv[3][64 * 64];
  __shared__ unsigned short lp[8][16][72];  // [wave] = A, [wave+4] = B

  const int tid = threadIdx.x, lane = tid & 63, wave = tid >> 6;
  const int ip = blockIdx.x, bh = blockIdx.y;
  const int qtA = ip;          // small q-tile (ip+1 kv tiles)
  const int qtB = 31 - ip;     // large q-tile (32-ip kv tiles)
  const int nt = qtB + 1;      // >= 17

  const unsigned short* Kb = K + bh * 2048 * 64;
  const unsigned short* Vb = Vt + bh * 64 * 2048;

  bf16x8 qfA[2], qfB[2];
  {
    const unsigned short* qr =
        Q + (bh * 2048 + qtA * 64 + wave * 16 + (lane & 15)) * 64 + ((lane >> 4) << 3);
    qfA[0] = *reinterpret_cast<const bf16x8*>(qr);
    qfA[1] = *reinterpret_cast<const bf16x8*>(qr + 32);
    qr = Q + (bh * 2048 + qtB * 64 + wave * 16 + (lane & 15)) * 64 + ((lane >> 4) << 3);
    qfB[0] = *reinterpret_cast<const bf16x8*>(qr);
    qfB[1] = *reinterpret_cast<const bf16x8*>(qr + 32);
  }

  f32x4 oA[4] = {}, oB[4] = {};
  float lA = 0.f, lB = 0.f;
  const int qloc = wave * 16 + (lane & 15);  // q within 64-row tile

  attn_stage(Kb, Vb, lk[0], lv[0], 0, tid);
  attn_stage(Kb, Vb, lk[1], lv[1], 64, tid);
  WAITVM(4);  // tile 0 landed
  BAR();

  for (int t = 0; t < nt; ++t) {
    const int nx = (t + 2 < nt) ? t + 2 : nt - 1;  // clamp: redundant stage
    const int sb = (t + 2) % 3, cb = t % 3;
    attn_stage(Kb, Vb, lk[sb], lv[sb], nx * 64, tid);
    WAITVM(8);  // tiles t+1, t+2 in flight; t drained
    BAR();
    SCHEDB();
    if (t <= qtA)
      attn_step_dual(lk[cb], lv[cb], lp[wave], lp[wave + 4], qfA, qfB, oA,
                     oB, lA, lB, lane, qloc, t == qtA);
    else
      attn_step(lk[cb], lv[cb], lp[wave + 4], qfB, oB, lB, lane, qloc,
                t == qtB);
    BAR();  // buf cb consumed by all before re-stage next iter
  }

  const int b = bh >> 4, hh = bh & 15;
  attn_epi(Ctx, lp[wave], oA, lA, b, hh, qtA * 64 + wave * 16, lane);
  attn_epi(Ctx, lp[wave + 4], oB, lB, b, hh, qtB * 64 + wave * 16, lane);
}

// ---------------- launch ----------------
extern "C" void kernel_launch(void* const* d_in, const int* in_sizes, int n_in,
                              void* d_out, int out_size, void* d_ws,
                              size_t ws_size, hipStream_t stream) {
  const float* x = (const float*)d_in[0];
  const float* Wq = (const float*)d_in[1];
  const float* bq = (const float*)d_in[2];
  const float* Wk = (const float*)d_in[3];
  const float* bk = (const float*)d_in[4];
  const float* Wv = (const float*)d_in[5];
  const float* bv = (const float*)d_in[6];
  const float* Wo = (const float*)d_in[7];
  const float* bo = (const float*)d_in[8];
  float* out = (float*)d_out;

  char* ws = (char*)d_ws;
  unsigned short* xb = (unsigned short*)(ws);                    // 8 MB
  unsigned short* wqb = (unsigned short*)(ws + (8u << 20));      // 2 MB
  unsigned short* wkb = (unsigned short*)(ws + (10u << 20));
  unsigned short* wvb = (unsigned short*)(ws + (12u << 20));
  unsigned short* wob = (unsigned short*)(ws + (14u << 20));
  unsigned short* Qb = (unsigned short*)(ws + (16u << 20));      // 8 MB
  unsigned short* Kb = (unsigned short*)(ws + (24u << 20));      // 8 MB
  unsigned short* Vtb = (unsigned short*)(ws + (32u << 20));     // 8 MB
  unsigned short* Ctx = (unsigned short*)(ws + (40u << 20));     // 8 MB

  k_cvt_all<<<8192, 256, 0, stream>>>(x, Wq, Wk, Wv, Wo, xb);

  k_gemm_qkv<<<dim3(8, 32, 3), 256, 0, stream>>>(xb, wqb, wkb, wvb, bq, bk, bv,
                                                 Qb, Kb, Vtb);
  k_attn<<<dim3(16, 32), 256, 0, stream>>>(Qb, Kb, Vtb, Ctx);
  k_gemm_out<<<dim3(16, 32), 256, 0, stream>>>(Ctx, wob, bo, out);
}

// Round 6
// 124.620 us; speedup vs baseline: 1.0828x; 1.0828x over previous
//
#include <hip/hip_runtime.h>

// Fused MHA: x->QKV proj (bf16 MFMA) -> causal flash attn -> O proj.
// B=2, T=2048, D=1024, H=16, HD=64.
// Round 6: GEMMs reverted to 2-buffer syncthreads loop (round-4 proven);
// + T2-lite LDS swizzle on staging; + LDS-transposed coalesced epilogues.
// Attn kept as round-5 (3-buf counted vmcnt).

#define DEV __device__ __forceinline__

typedef __attribute__((ext_vector_type(8))) __bf16 bf16x8;
typedef __attribute__((ext_vector_type(4))) float f32x4;

DEV unsigned short f2bf(float f) {
  union { float f; unsigned u; } c;
  c.f = f;
  unsigned u = c.u + 0x7FFFu + ((c.u >> 16) & 1u);  // RTNE
  return (unsigned short)(u >> 16);
}

DEV unsigned cvtpk(float lo, float hi) {
  unsigned r;
  asm("v_cvt_pk_bf16_f32 %0, %1, %2" : "=v"(r) : "v"(lo), "v"(hi));
  return r;
}

DEV void gload16(const unsigned short* g, unsigned short* l) {
  __builtin_amdgcn_global_load_lds(
      (const __attribute__((address_space(1))) unsigned int*)g,
      (__attribute__((address_space(3))) unsigned int*)l, 16, 0, 0);
}

DEV f32x4 mfma16(bf16x8 a, bf16x8 b, f32x4 c) {
  return __builtin_amdgcn_mfma_f32_16x16x32_bf16(a, b, c, 0, 0, 0);
}

#define WAITVM(n) asm volatile("s_waitcnt vmcnt(" #n ")" ::: "memory")
#define WAITLGKM() asm volatile("s_waitcnt lgkmcnt(0)" ::: "memory")
#define BAR() __builtin_amdgcn_s_barrier()
#define SCHEDB() __builtin_amdgcn_sched_barrier(0)

// ---------------- fp32 -> bf16 convert (all 5 tensors, one launch) -------
__global__ __launch_bounds__(256) void k_cvt_all(
    const float* __restrict__ x, const float* __restrict__ wq,
    const float* __restrict__ wk, const float* __restrict__ wv,
    const float* __restrict__ wo, unsigned short* __restrict__ dst) {
  int i = blockIdx.x * blockDim.x + threadIdx.x;  // float4 index
  const float* s;
  int off;
  if (i < 1048576) {
    s = x; off = i;
  } else {
    int j = i - 1048576;
    int w = j >> 18;
    off = j & 262143;
    s = (w == 0) ? wq : (w == 1) ? wk : (w == 2) ? wv : wo;
  }
  float4 v = reinterpret_cast<const float4*>(s)[off];
  uint2 o;
  o.x = (unsigned)f2bf(v.x) | ((unsigned)f2bf(v.y) << 16);
  o.y = (unsigned)f2bf(v.z) | ((unsigned)f2bf(v.w) << 16);
  reinterpret_cast<uint2*>(dst)[i] = o;
}

// ---------------- 128x128 bf16 GEMM core (C = A * W^T), K=1024 ----------
// 2-buffer double-buffered staging (round-4 structure), swizzled LDS:
// 16B chunk at (row, cb) holds global bytes cb ^ ((row&3)<<4) of the row's
// 64B K-slice; reads apply the same XOR (both-sides swizzle).
DEV void gemm_stage(const unsigned short* __restrict__ A,
                    const unsigned short* __restrict__ W,
                    unsigned short* la, unsigned short* lb,
                    int m0, int n0, int k0, int tid) {
#pragma unroll
  for (int i = 0; i < 2; ++i) {
    const int c = i * 256 + tid;
    const int row = c >> 2;
    const int scb = (((c & 3) << 4)) ^ ((row & 3) << 4);
    gload16(A + (m0 + row) * 1024 + k0 + (scb >> 1),
            (unsigned short*)((char*)la + c * 16));
    gload16(W + (n0 + row) * 1024 + k0 + (scb >> 1),
            (unsigned short*)((char*)lb + c * 16));
  }
}

DEV void gemm_core_128(const unsigned short* __restrict__ A,
                       const unsigned short* __restrict__ W,
                       unsigned short* la0, unsigned short* lb0,
                       int m0, int n0, f32x4 (&acc)[4][4]) {
  const int tid = threadIdx.x;
  const int lane = tid & 63;
  const int wave = tid >> 6;
  const int wm = (wave >> 1) * 64, wn = (wave & 1) * 64;
  const int g16 = ((lane >> 4) << 4);
  const int sx = (lane & 3) << 4;  // read-side swizzle (row&3 == lane&3)

  gemm_stage(A, W, la0, lb0, m0, n0, 0, tid);
  __syncthreads();

  for (int kt = 0; kt < 32; ++kt) {
    const int cur = kt & 1;
    unsigned short* la = la0 + cur * 4096;
    unsigned short* lb = lb0 + cur * 4096;
    if (kt + 1 < 32)
      gemm_stage(A, W, la0 + (cur ^ 1) * 4096, lb0 + (cur ^ 1) * 4096, m0, n0,
                 (kt + 1) * 32, tid);
    bf16x8 af[4], bfr[4];
#pragma unroll
    for (int m = 0; m < 4; ++m)
      af[m] = *reinterpret_cast<const bf16x8*>(
          (char*)la + (wm + m * 16 + (lane & 15)) * 64 + (g16 ^ sx));
#pragma unroll
    for (int n = 0; n < 4; ++n)
      bfr[n] = *reinterpret_cast<const bf16x8*>(
          (char*)lb + (wn + n * 16 + (lane & 15)) * 64 + (g16 ^ sx));
#pragma unroll
    for (int m = 0; m < 4; ++m)
#pragma unroll
      for (int n = 0; n < 4; ++n)
        acc[m][n] = mfma16(af[m], bfr[n], acc[m][n]);
    __syncthreads();
  }
}

// ---------------- QKV projection ----------------
// Q is pre-scaled by 0.125*log2(e) so attn scores land in exp2 domain.
// Epilogue: per-wave LDS transpose -> coalesced b128 stores.
__global__ __launch_bounds__(256) void k_gemm_qkv(
    const unsigned short* __restrict__ X, const unsigned short* __restrict__ Wq,
    const unsigned short* __restrict__ Wk, const unsigned short* __restrict__ Wv,
    const float* __restrict__ bq, const float* __restrict__ bk,
    const float* __restrict__ bv, unsigned short* __restrict__ Qo,
    unsigned short* __restrict__ Ko, unsigned short* __restrict__ Vo) {
  __shared__ unsigned short ls[16384];  // la 2x4096 | lb 2x4096 (32 KB)
  const int mode = blockIdx.z;
  const unsigned short* W = (mode == 0) ? Wq : (mode == 1) ? Wk : Wv;
  const float* bias = (mode == 0) ? bq : (mode == 1) ? bk : bv;
  const int m0 = blockIdx.y * 128, n0 = blockIdx.x * 128;
  f32x4 acc[4][4] = {};
  gemm_core_128(X, W, ls, ls + 8192, m0, n0, acc);

  const int lane = threadIdx.x & 63, wave = threadIdx.x >> 6;
  const int l15 = lane & 15, g = lane >> 4;
  const int wm = (wave >> 1) * 64, wn = (wave & 1) * 64;
  unsigned short* lw = ls + wave * 4096;  // per-wave 8KB region

  const int h = (n0 + wn) >> 6;          // single head per wave col-block
  const int rbase0 = m0 + wm;            // 64-aligned -> same b for 64 rows
  const int b = rbase0 >> 11;
  const int tb0 = rbase0 & 2047;

  if (mode == 2) {
    // V^T: LDS tile [hd 64][t 64], 8B-block-swizzled rows
#pragma unroll
    for (int m = 0; m < 4; ++m)
#pragma unroll
      for (int n = 0; n < 4; ++n) {
        const float bb = bias[n0 + wn + n * 16 + l15];
        uint2 w;
        w.x = cvtpk(acc[m][n][0] + bb, acc[m][n][1] + bb);
        w.y = cvtpk(acc[m][n][2] + bb, acc[m][n][3] + bb);
        *reinterpret_cast<uint2*>(
            (char*)lw + (n * 16 + l15) * 128 +
            ((((m << 2) + g) ^ (l15 & 14)) << 3)) = w;
      }
    WAITLGKM();
    SCHEDB();
#pragma unroll
    for (int it = 0; it < 8; ++it) {
      const int hd = (lane >> 3) + it * 8;
      const int jj = ((lane & 7) << 1) ^ (hd & 14);
      uint4 v = *reinterpret_cast<const uint4*>((char*)lw + hd * 128 + jj * 8);
      *reinterpret_cast<uint4*>(
          &Vo[((((b << 4) + h) << 6) + hd) * 2048 + tb0 + ((lane & 7) << 3)]) =
          v;
    }
  } else {
    // Q/K: LDS tile [t 64][hd 64]
    const float sc = (mode == 0) ? 0.180336880f : 1.0f;  // 0.125*log2(e)
#pragma unroll
    for (int m = 0; m < 4; ++m)
#pragma unroll
      for (int n = 0; n < 4; ++n) {
        const float bb = bias[n0 + wn + n * 16 + l15];
#pragma unroll
        for (int r = 0; r < 4; ++r)
          lw[(m * 16 + (g << 2) + r) * 64 + n * 16 + l15] =
              f2bf((acc[m][n][r] + bb) * sc);
      }
    WAITLGKM();
    SCHEDB();
    unsigned short* dst = (mode == 0) ? Qo : Ko;
#pragma unroll
    for (int it = 0; it < 8; ++it) {
      const int rr = (lane >> 3) + it * 8;
      const int ck = (lane & 7) * 8;
      uint4 v = *reinterpret_cast<const uint4*>(&lw[rr * 64 + ck]);
      *reinterpret_cast<uint4*>(
          &dst[(((b << 4) + h) * 2048 + tb0 + rr) * 64 + ck]) = v;
    }
  }
}

// ---------------- output projection (128x64 tiles, fp32 out + bias) ------
__global__ __launch_bounds__(256) void k_gemm_out(
    const unsigned short* __restrict__ Ctx, const unsigned short* __restrict__ Wo,
    const float* __restrict__ bo, float* __restrict__ Out) {
  __shared__ unsigned short ls[16384];  // la 2x4096 | lb 2x2048 | epi regions
  unsigned short* la0 = ls;
  unsigned short* lb0 = ls + 8192;
  const int tid = threadIdx.x;
  const int lane = tid & 63, wave = tid >> 6;
  const int l15 = lane & 15, g = lane >> 4;
  const int m0 = blockIdx.y * 128, n0 = blockIdx.x * 64;
  const int wm = (wave >> 1) * 64, wn = (wave & 1) * 32;
  const int g16 = (g << 4);
  const int sx = (lane & 3) << 4;
  f32x4 acc[4][2] = {};

#define STG_OUT(buf, k0)                                                     \
  {                                                                          \
    _Pragma("unroll") for (int i = 0; i < 2; ++i) {                          \
      const int c = i * 256 + tid;                                           \
      const int row = c >> 2;                                                \
      const int scb = (((c & 3) << 4)) ^ ((row & 3) << 4);                   \
      gload16(Ctx + (m0 + row) * 1024 + (k0) + (scb >> 1),                   \
              (unsigned short*)((char*)(la0 + (buf)*4096) + c * 16));        \
    }                                                                        \
    {                                                                        \
      const int row = tid >> 2;                                              \
      const int scb = (((tid & 3) << 4)) ^ ((row & 3) << 4);                 \
      gload16(Wo + (n0 + row) * 1024 + (k0) + (scb >> 1),                    \
              (unsigned short*)((char*)(lb0 + (buf)*2048) + tid * 16));      \
    }                                                                        \
  }

  STG_OUT(0, 0);
  __syncthreads();

  for (int kt = 0; kt < 32; ++kt) {
    const int cur = kt & 1;
    unsigned short* la = la0 + cur * 4096;
    unsigned short* lb = lb0 + cur * 2048;
    if (kt + 1 < 32) STG_OUT(cur ^ 1, (kt + 1) * 32);
    bf16x8 af[4], bfr[2];
#pragma unroll
    for (int m = 0; m < 4; ++m)
      af[m] = *reinterpret_cast<const bf16x8*>(
          (char*)la + (wm + m * 16 + l15) * 64 + (g16 ^ sx));
#pragma unroll
    for (int n = 0; n < 2; ++n)
      bfr[n] = *reinterpret_cast<const bf16x8*>(
          (char*)lb + (wn + n * 16 + l15) * 64 + (g16 ^ sx));
#pragma unroll
    for (int m = 0; m < 4; ++m)
#pragma unroll
      for (int n = 0; n < 2; ++n)
        acc[m][n] = mfma16(af[m], bfr[n], acc[m][n]);
    __syncthreads();
  }
#undef STG_OUT

  // epilogue: f32 [64][32] per-wave LDS tile -> coalesced float4 stores
  float* lwf = (float*)(ls + wave * 4096);
#pragma unroll
  for (int m = 0; m < 4; ++m)
#pragma unroll
    for (int n = 0; n < 2; ++n) {
      const float bb = bo[n0 + wn + n * 16 + l15];
#pragma unroll
      for (int r = 0; r < 4; ++r)
        lwf[(m * 16 + (g << 2) + r) * 32 + n * 16 + l15] = acc[m][n][r] + bb;
    }
  WAITLGKM();
  SCHEDB();
#pragma unroll
  for (int it = 0; it < 8; ++it) {
    const int rr = (lane >> 3) + it * 8;
    const int ck = (lane & 7) * 4;
    float4 v = *reinterpret_cast<const float4*>(&lwf[rr * 32 + ck]);
    *reinterpret_cast<float4*>(&Out[(m0 + wm + rr) * 1024 + n0 + wn + ck]) = v;
  }
}

// ---------------- causal flash attention (swapped-QK^T, fixed-max) -------
// Q: [32][2048][64] bf16 (pre-scaled 0.125*log2e), K: [32][2048][64],
// Vt: [32][64][2048]. Lane owns q = lane&15, k-subset = 16n+4g+r (g=lane>>4).
// No max tracking: P = exp2(S2) directly; normalized by l at end.

DEV void attn_stage(const unsigned short* __restrict__ Kb,
                    const unsigned short* __restrict__ Vb,
                    unsigned short* lk, unsigned short* lv, int kv0, int tid) {
#pragma unroll
  for (int i = 0; i < 2; ++i) {
    const int c = i * 256 + tid;
    const int row = c >> 3;
    const int cb = (c & 7) << 4;
    const int scb = cb ^ ((row & 7) << 4);  // pre-swizzle global source
    gload16(Kb + (kv0 + row) * 64 + (scb >> 1),
            (unsigned short*)((char*)lk + c * 16));
    gload16(Vb + row * 2048 + kv0 + (scb >> 1),
            (unsigned short*)((char*)lv + c * 16));
  }
}

// single-tile step (B only)
DEV void attn_step(const unsigned short* lk, const unsigned short* lv,
                   unsigned short (&lp)[16][72], const bf16x8 (&qf)[2],
                   f32x4 (&o)[4], float& lsum, int lane, int qloc, bool diag) {
  const int g = lane >> 4;
  f32x4 st[4];
#pragma unroll
  for (int n = 0; n < 4; ++n) {
    f32x4 z = {};
    const int row = n * 16 + (lane & 15);
    const int sw = (row & 7) << 4;
#pragma unroll
    for (int kk = 0; kk < 2; ++kk) {
      bf16x8 kf = *reinterpret_cast<const bf16x8*>(
          (char*)lk + row * 128 + ((kk * 64 + (g << 4)) ^ sw));
      z = mfma16(kf, qf[kk], z);
    }
    st[n] = z;
  }
  if (diag) {
#pragma unroll
    for (int n = 0; n < 4; ++n)
#pragma unroll
      for (int r = 0; r < 4; ++r)
        if (n * 16 + g * 4 + r > qloc) st[n][r] = -1e30f;
  }
  float rs = 0.f;
#pragma unroll
  for (int n = 0; n < 4; ++n)
#pragma unroll
    for (int r = 0; r < 4; ++r) {
      float p = exp2f(st[n][r]);
      st[n][r] = p;
      rs += p;
    }
  lsum += rs;
#pragma unroll
  for (int n = 0; n < 4; ++n) {
    uint2 w;
    w.x = cvtpk(st[n][0], st[n][1]);
    w.y = cvtpk(st[n][2], st[n][3]);
    *reinterpret_cast<uint2*>(&lp[lane & 15][n * 16 + g * 4]) = w;
  }
  WAITLGKM();
  SCHEDB();
  bf16x8 pb[2];
  pb[0] = *reinterpret_cast<const bf16x8*>(&lp[lane & 15][g * 8]);
  pb[1] = *reinterpret_cast<const bf16x8*>(&lp[lane & 15][32 + g * 8]);
#pragma unroll
  for (int h = 0; h < 4; ++h) {
    const int row = h * 16 + (lane & 15);
    const int sw = (row & 7) << 4;
#pragma unroll
    for (int kk = 0; kk < 2; ++kk) {
      bf16x8 vf = *reinterpret_cast<const bf16x8*>(
          (char*)lv + row * 128 + ((kk * 64 + (g << 4)) ^ sw));
      o[h] = mfma16(vf, pb[kk], o[h]);
    }
  }
}

// dual-tile step: shares kf/vf fragment loads between q-tiles A and B.
DEV void attn_step_dual(const unsigned short* lk, const unsigned short* lv,
                        unsigned short (&lpA)[16][72],
                        unsigned short (&lpB)[16][72],
                        const bf16x8 (&qfA)[2], const bf16x8 (&qfB)[2],
                        f32x4 (&oA)[4], f32x4 (&oB)[4], float& lsA, float& lsB,
                        int lane, int qloc, bool diagA) {
  const int g = lane >> 4;
  f32x4 sA[4], sB[4];
#pragma unroll
  for (int n = 0; n < 4; ++n) {
    f32x4 zA = {}, zB = {};
    const int row = n * 16 + (lane & 15);
    const int sw = (row & 7) << 4;
#pragma unroll
    for (int kk = 0; kk < 2; ++kk) {
      bf16x8 kf = *reinterpret_cast<const bf16x8*>(
          (char*)lk + row * 128 + ((kk * 64 + (g << 4)) ^ sw));
      zB = mfma16(kf, qfB[kk], zB);
      zA = mfma16(kf, qfA[kk], zA);
    }
    sA[n] = zA;
    sB[n] = zB;
  }
  if (diagA) {
#pragma unroll
    for (int n = 0; n < 4; ++n)
#pragma unroll
      for (int r = 0; r < 4; ++r)
        if (n * 16 + g * 4 + r > qloc) sA[n][r] = -1e30f;
  }
  float rsA = 0.f, rsB = 0.f;
#pragma unroll
  for (int n = 0; n < 4; ++n)
#pragma unroll
    for (int r = 0; r < 4; ++r) {
      float pA = exp2f(sA[n][r]);
      float pB = exp2f(sB[n][r]);
      sA[n][r] = pA;
      sB[n][r] = pB;
      rsA += pA;
      rsB += pB;
    }
  lsA += rsA;
  lsB += rsB;
#pragma unroll
  for (int n = 0; n < 4; ++n) {
    uint2 wA, wB;
    wA.x = cvtpk(sA[n][0], sA[n][1]);
    wA.y = cvtpk(sA[n][2], sA[n][3]);
    wB.x = cvtpk(sB[n][0], sB[n][1]);
    wB.y = cvtpk(sB[n][2], sB[n][3]);
    *reinterpret_cast<uint2*>(&lpA[lane & 15][n * 16 + g * 4]) = wA;
    *reinterpret_cast<uint2*>(&lpB[lane & 15][n * 16 + g * 4]) = wB;
  }
  WAITLGKM();
  SCHEDB();
  bf16x8 pbA[2], pbB[2];
  pbA[0] = *reinterpret_cast<const bf16x8*>(&lpA[lane & 15][g * 8]);
  pbA[1] = *reinterpret_cast<const bf16x8*>(&lpA[lane & 15][32 + g * 8]);
  pbB[0] = *reinterpret_cast<const bf16x8*>(&lpB[lane & 15][g * 8]);
  pbB[1] = *reinterpret_cast<const bf16x8*>(&lpB[lane & 15][32 + g * 8]);
#pragma unroll
  for (int h = 0; h < 4; ++h) {
    const int row = h * 16 + (lane & 15);
    const int sw = (row & 7) << 4;
#pragma unroll
    for (int kk = 0; kk < 2; ++kk) {
      bf16x8 vf = *reinterpret_cast<const bf16x8*>(
          (char*)lv + row * 128 + ((kk * 64 + (g << 4)) ^ sw));
      oB[h] = mfma16(vf, pbB[kk], oB[h]);
      oA[h] = mfma16(vf, pbA[kk], oA[h]);
    }
  }
}

DEV void attn_epi(unsigned short* __restrict__ Ctx,
                  unsigned short (&lp)[16][72], const f32x4 (&o)[4],
                  float lsum, int b, int hh, int qbase, int lane) {
  float lt = lsum;
  lt += __shfl_xor(lt, 16);
  lt += __shfl_xor(lt, 32);
  const float inv = 1.f / lt;
  const int g = lane >> 4;
#pragma unroll
  for (int h = 0; h < 4; ++h) {
    uint2 w;
    w.x = cvtpk(o[h][0] * inv, o[h][1] * inv);
    w.y = cvtpk(o[h][2] * inv, o[h][3] * inv);
    *reinterpret_cast<uint2*>(&lp[lane & 15][h * 16 + g * 4]) = w;
  }
  WAITLGKM();
  SCHEDB();
#pragma unroll
  for (int it = 0; it < 2; ++it) {
    const int q = (lane >> 3) + it * 8;
    const int ck = (lane & 7) * 8;
    uint4 v = *reinterpret_cast<const uint4*>(&lp[q][ck]);
    *reinterpret_cast<uint4*>(
        &Ctx[(b * 2048 + qbase + q) * 1024 + hh * 64 + ck]) = v;
  }
}

__global__ __launch_bounds__(256) void k_attn(
    const unsigned short* __restrict__ Q, const unsigned short* __restrict__ K,
    const unsigned short* __restrict__ Vt, unsigned short* __restrict__ Ctx) {
  __shared__ unsigned short lk[3][64 * 64];
  __shared__ unsigned short lv[3][64 * 64];
  __shared__ unsigned short lp[8][16][72];  // [wave] = A, [wave+4] = B

  const int tid = threadIdx.x, lane = tid & 63, wave = tid >> 6;
  const int ip = blockIdx.x, bh = blockIdx.y;
  const int qtA = ip;          // small q-tile (ip+1 kv tiles)
  const int qtB = 31 - ip;     // large q-tile (32-ip kv tiles)
  const int nt = qtB + 1;      // >= 17

  const unsigned short* Kb = K + bh * 2048 * 64;
  const unsigned short* Vb = Vt + bh * 64 * 2048;

  bf16x8 qfA[2], qfB[2];
  {
    const unsigned short* qr =
        Q + (bh * 2048 + qtA * 64 + wave * 16 + (lane & 15)) * 64 + ((lane >> 4) << 3);
    qfA[0] = *reinterpret_cast<const bf16x8*>(qr);
    qfA[1] = *reinterpret_cast<const bf16x8*>(qr + 32);
    qr = Q + (bh * 2048 + qtB * 64 + wave * 16 + (lane & 15)) * 64 + ((lane >> 4) << 3);
    qfB[0] = *reinterpret_cast<const bf16x8*>(qr);
    qfB[1] = *reinterpret_cast<const bf16x8*>(qr + 32);
  }

  f32x4 oA[4] = {}, oB[4] = {};
  float lA = 0.f, lB = 0.f;
  const int qloc = wave * 16 + (lane & 15);  // q within 64-row tile

  attn_stage(Kb, Vb, lk[0], lv[0], 0, tid);
  attn_stage(Kb, Vb, lk[1], lv[1], 64, tid);
  WAITVM(4);  // tile 0 landed
  BAR();

  for (int t = 0; t < nt; ++t) {
    const int nx = (t + 2 < nt) ? t + 2 : nt - 1;  // clamp: redundant stage
    const int sb = (t + 2) % 3, cb = t % 3;
    attn_stage(Kb, Vb, lk[sb], lv[sb], nx * 64, tid);
    WAITVM(8);  // tiles t+1, t+2 in flight; t drained
    BAR();
    SCHEDB();
    if (t <= qtA)
      attn_step_dual(lk[cb], lv[cb], lp[wave], lp[wave + 4], qfA, qfB, oA,
                     oB, lA, lB, lane, qloc, t == qtA);
    else
      attn_step(lk[cb], lv[cb], lp[wave + 4], qfB, oB, lB, lane, qloc,
                t == qtB);
    BAR();  // buf cb consumed by all before re-stage next iter
  }

  const int b = bh >> 4, hh = bh & 15;
  attn_epi(Ctx, lp[wave], oA, lA, b, hh, qtA * 64 + wave * 16, lane);
  attn_epi(Ctx, lp[wave + 4], oB, lB, b, hh, qtB * 64 + wave * 16, lane);
}

// ---------------- launch ----------------
extern "C" void kernel_launch(void* const* d_in, const int* in_sizes, int n_in,
                              void* d_out, int out_size, void* d_ws,
                              size_t ws_size, hipStream_t stream) {
  const float* x = (const float*)d_in[0];
  const float* Wq = (const float*)d_in[1];
  const float* bq = (const float*)d_in[2];
  const float* Wk = (const float*)d_in[3];
  const float* bk = (const float*)d_in[4];
  const float* Wv = (const float*)d_in[5];
  const float* bv = (const float*)d_in[6];
  const float* Wo = (const float*)d_in[7];
  const float* bo = (const float*)d_in[8];
  float* out = (float*)d_out;

  char* ws = (char*)d_ws;
  unsigned short* xb = (unsigned short*)(ws);                    // 8 MB
  unsigned short* wqb = (unsigned short*)(ws + (8u << 20));      // 2 MB
  unsigned short* wkb = (unsigned short*)(ws + (10u << 20));
  unsigned short* wvb = (unsigned short*)(ws + (12u << 20));
  unsigned short* wob = (unsigned short*)(ws + (14u << 20));
  unsigned short* Qb = (unsigned short*)(ws + (16u << 20));      // 8 MB
  unsigned short* Kb = (unsigned short*)(ws + (24u << 20));      // 8 MB
  unsigned short* Vtb = (unsigned short*)(ws + (32u << 20));     // 8 MB
  unsigned short* Ctx = (unsigned short*)(ws + (40u << 20));     // 8 MB

  k_cvt_all<<<8192, 256, 0, stream>>>(x, Wq, Wk, Wv, Wo, xb);

  k_gemm_qkv<<<dim3(8, 32, 3), 256, 0, stream>>>(xb, wqb, wkb, wvb, bq, bk, bv,
                                                 Qb, Kb, Vtb);
  k_attn<<<dim3(16, 32), 256, 0, stream>>>(Qb, Kb, Vtb, Ctx);
  k_gemm_out<<<dim3(16, 32), 256, 0, stream>>>(Ctx, wob, bo, out);
}